// Round 15
// baseline (45.206 us; speedup 1.0000x reference)
//
#include <hip/hip_runtime.h>

typedef __attribute__((ext_vector_type(8))) short bf16x8;
typedef __attribute__((ext_vector_type(4))) float f32x4;

constexpr int TN = 8192;   // tokens
constexpr int DN = 4096;   // model dim
constexpr int EN = 64;     // experts

constexpr int NS     = DN / 32;     // 128 K32 slots total
constexpr int KSPLIT = 16;          // k-sixteenth per block
constexpr int SLOTS  = NS / KSPLIT; // 8 K32 slots per block (256 k)
constexpr int RB     = 128;         // rows per block (8 waves x 16)
constexpr int RW     = 16;          // rows per wave

__device__ __forceinline__ unsigned short f2bf(float f) {  // RNE f32->bf16
    unsigned u = __builtin_bit_cast(unsigned, f);
    u += 0x7FFFu + ((u >> 16) & 1u);
    return (unsigned short)(u >> 16);
}
__device__ __forceinline__ float bf2f(unsigned short h) {
    unsigned u = ((unsigned)h) << 16;
    return __builtin_bit_cast(float, u);
}
// RNE hi/lo bf16 split of an f32 pair, packed (f1<<16|f0); ~14 VALU/pair.
__device__ __forceinline__ void split_pair(float f0, float f1,
                                           unsigned& hi, unsigned& lo) {
    unsigned u0 = __builtin_bit_cast(unsigned, f0);
    unsigned u1 = __builtin_bit_cast(unsigned, f1);
    unsigned r0 = u0 + 0x7FFFu + ((u0 >> 16) & 1u);
    unsigned r1 = u1 + 0x7FFFu + ((u1 >> 16) & 1u);
    hi = __builtin_amdgcn_perm(r1, r0, 0x07060302u);  // {r1.hi16, r0.hi16}
    float h0 = __builtin_bit_cast(float, r0 & 0xFFFF0000u);
    float h1 = __builtin_bit_cast(float, r1 & 0xFFFF0000u);
    unsigned v0 = __builtin_bit_cast(unsigned, f0 - h0);
    unsigned v1 = __builtin_bit_cast(unsigned, f1 - h1);
    unsigned s0 = v0 + 0x7FFFu + ((v0 >> 16) & 1u);
    unsigned s1 = v1 + 0x7FFFu + ((v1 >> 16) & 1u);
    lo = __builtin_amdgcn_perm(s1, s0, 0x07060302u);
}

// Kernel 0: split wg into hi/lo bf16 planes in MFMA-fragment order:
// BF[p][s][et][lane*8+j] = plane_p( wg[et*16+(lane&15)][s*32+(lane>>4)*8+j] ).
__global__ __launch_bounds__(256)
void wg_frag_kernel(const float* __restrict__ wg, unsigned short* __restrict__ BF) {
    const int gid = blockIdx.x * 256 + threadIdx.x;  // 65536 items
    const int l  = gid & 63;
    const int et = (gid >> 6) & 3;
    const int s  = (gid >> 8) & (NS - 1);
    const int p  = gid >> 15;
    const int e  = et * 16 + (l & 15);
    const int k  = s * 32 + (l >> 4) * 8;

    const float* src = wg + (size_t)e * DN + k;
    float4 v0 = *reinterpret_cast<const float4*>(src);
    float4 v1 = *reinterpret_cast<const float4*>(src + 4);
    float f[8] = {v0.x, v0.y, v0.z, v0.w, v1.x, v1.y, v1.z, v1.w};
    unsigned short o[8];
#pragma unroll
    for (int j = 0; j < 8; ++j) {
        unsigned short h = f2bf(f[j]);
        o[j] = p ? f2bf(f[j] - bf2f(h)) : h;
    }
    unsigned short* dst = BF + (((size_t)p * NS + s) * 4 + et) * 512 + (size_t)l * 8;
    *reinterpret_cast<ushort4*>(dst)     = make_ushort4(o[0], o[1], o[2], o[3]);
    *reinterpret_cast<ushort4*>(dst + 4) = make_ushort4(o[4], o[5], o[6], o[7]);
}

// Kernel 1: B-in-LDS split-bf16 MFMA GEMM, K-split partials, HIGH OCCUPANCY.
// Grid = 64 row-tiles x 16 ksplits = 1024 blocks, 512 thr = 8 waves, 64KB
// LDS -> 2 resident blocks/CU = 16 waves/CU = 4 waves/SIMD (launch_bounds
// caps VGPR at 128; acc is only 16 regs at RW=16). B (hi+lo, 64KB) staged
// into LDS once; fragments re-read per phase via ds_read_b128 (~150cyc,
// TLP-hidden at 4 waves/SIMD). A gathered per-lane from x, split hi/lo
// in-register, depth-2 ping-pong. 3-product scheme (hh+lh+hl; ll dropped,
// error sigma ~2e-6 << budget). No in-loop barriers.
__global__ __launch_bounds__(512, 4)
void gate_gemm_kernel(const float* __restrict__ x,
                      const unsigned short* __restrict__ BF,
                      float* __restrict__ part) {
    __shared__ uint4 LB[SLOTS * 512];   // 64 KB: [slot][plane(2)][et*64+lane]

    const int tid  = threadIdx.x;
    const int lane = tid & 63;
    const int w    = tid >> 6;          // wave 0..7
    const int rt   = blockIdx.x >> 4;
    const int ks   = blockIdx.x & 15;   // round-robin -> 2 B-16ths per XCD L2
    const int r0   = rt * RB;

    const int fr = lane & 15;           // fragment row (A) / expert col (B)
    const int g  = lane >> 4;           // k-group within K=32

    // stage B: 4096 uint4 (64KB), 8 iters x 512 threads, fully coalesced
    {
        const uint4* gh = reinterpret_cast<const uint4*>(BF);
        const uint4* gl = gh + 32768;   // lo plane at +512KB
#pragma unroll
        for (int i = 0; i < 8; ++i) {
            int e = tid + i * 512;
            int slot = e >> 9, plane = (e >> 8) & 1, off = e & 255;
            int gidx = (ks * SLOTS + slot) * 256 + off;
            LB[e] = plane ? gl[gidx] : gh[gidx];
        }
    }
    __syncthreads();                    // only barrier; LDS read-only after

    const float* xa = x + (size_t)(r0 + w * RW + fr) * DN + g * 8;

    f32x4 acc[4] = {};                  // 4 expert tiles (16 VGPR)
    float4 XA[2][2];                    // depth-2 A fp32 ping-pong (16 VGPR)

    auto loadA = [&](int set, int t) {
        const float* p = xa + (size_t)(ks * SLOTS + t) * 32;
        XA[set][0] = *reinterpret_cast<const float4*>(p);
        XA[set][1] = *reinterpret_cast<const float4*>(p + 4);
    };
    auto compute = [&](int set, int t) {
        bf16x8 bh[4], bl[4];
#pragma unroll
        for (int et = 0; et < 4; ++et) {
            bh[et] = __builtin_bit_cast(bf16x8, LB[t * 512 + et * 64 + lane]);
            bl[et] = __builtin_bit_cast(bf16x8, LB[t * 512 + 256 + et * 64 + lane]);
        }
        float f[8] = {XA[set][0].x, XA[set][0].y, XA[set][0].z, XA[set][0].w,
                      XA[set][1].x, XA[set][1].y, XA[set][1].z, XA[set][1].w};
        unsigned uh[4], ul[4];
#pragma unroll
        for (int q = 0; q < 4; ++q)
            split_pair(f[2 * q], f[2 * q + 1], uh[q], ul[q]);
        uint4 vh = make_uint4(uh[0], uh[1], uh[2], uh[3]);
        uint4 vl = make_uint4(ul[0], ul[1], ul[2], ul[3]);
        bf16x8 ah = __builtin_bit_cast(bf16x8, vh);
        bf16x8 al = __builtin_bit_cast(bf16x8, vl);
        // 3 products, product-outer: acc reuse distance = 4
#pragma unroll
        for (int et = 0; et < 4; ++et)
            acc[et] = __builtin_amdgcn_mfma_f32_16x16x32_bf16(ah, bh[et], acc[et], 0, 0, 0);
#pragma unroll
        for (int et = 0; et < 4; ++et)
            acc[et] = __builtin_amdgcn_mfma_f32_16x16x32_bf16(al, bh[et], acc[et], 0, 0, 0);
#pragma unroll
        for (int et = 0; et < 4; ++et)
            acc[et] = __builtin_amdgcn_mfma_f32_16x16x32_bf16(ah, bl[et], acc[et], 0, 0, 0);
    };

    loadA(0, 0);
    loadA(1, 1);
#pragma unroll
    for (int t = 0; t < SLOTS; ++t) {   // full unroll: set indices static
        compute(t & 1, t);              // WAR-safe: compute before overwrite
        if (t + 2 < SLOTS) loadA(t & 1, t + 2);
        asm volatile("" ::: "memory");  // pin per-phase issue order
    }

    // partial store straight from registers (each wave owns distinct rows).
    // C/D layout: col = lane&15, row = (lane>>4)*4 + reg  [m89]
    float* dst = part + ((size_t)ks * TN + r0 + w * RW) * EN;
#pragma unroll
    for (int et = 0; et < 4; ++et)
#pragma unroll
        for (int r = 0; r < 4; ++r)
            dst[(size_t)(g * 4 + r) * EN + et * 16 + fr] = acc[et][r];
}

// Kernel 2: sum 16 partials, top-1 softmax. 16 threads/row (4 experts each),
// shuffle-reduce. out[0..TN) = argmax idx (float), out[TN..2TN) = max gate.
__global__ __launch_bounds__(256)
void top1_softmax_kernel(const float* __restrict__ part, float* __restrict__ out) {
    const int gid = blockIdx.x * blockDim.x + threadIdx.x;
    const int row = gid >> 4;
    const int eg  = gid & 15;
    if (row >= TN) return;

    float v[4] = {};
#pragma unroll
    for (int h = 0; h < KSPLIT; ++h) {
        float4 t = *reinterpret_cast<const float4*>(
            &part[((size_t)h * TN + row) * EN + eg * 4]);
        v[0] += t.x; v[1] += t.y; v[2] += t.z; v[3] += t.w;
    }
    float m = v[0];
    int idx = eg * 4;
#pragma unroll
    for (int j = 1; j < 4; ++j)
        if (v[j] > m) { m = v[j]; idx = eg * 4 + j; }  // strict >: first occurrence
#pragma unroll
    for (int d = 1; d < 16; d <<= 1) {
        float om = __shfl_xor(m, d);
        int   oi = __shfl_xor(idx, d);
        if (om > m || (om == m && oi < idx)) { m = om; idx = oi; }
    }
    float s = 0.0f;
#pragma unroll
    for (int j = 0; j < 4; ++j) s += __expf(v[j] - m);
#pragma unroll
    for (int d = 1; d < 16; d <<= 1) s += __shfl_xor(s, d);
    if (eg == 0) {
        out[row]      = (float)idx;     // argmax index
        out[TN + row] = 1.0f / s;       // max gate = 1/sum(exp(l-lmax))
    }
}

extern "C" void kernel_launch(void* const* d_in, const int* in_sizes, int n_in,
                              void* d_out, int out_size, void* d_ws, size_t ws_size,
                              hipStream_t stream) {
    const float* x  = (const float*)d_in[0];
    const float* wg = (const float*)d_in[1];
    float* out = (float*)d_out;

    constexpr size_t BF_BYTES = (size_t)2 * NS * 4 * 512 * 2;  // 1 MB
    unsigned short* BF = (unsigned short*)d_ws;
    float* part = (float*)((char*)d_ws + BF_BYTES);            // 32 MB partials

    wg_frag_kernel<<<dim3(256), dim3(256), 0, stream>>>(wg, BF);
    gate_gemm_kernel<<<dim3((TN / RB) * KSPLIT), dim3(512), 0, stream>>>(x, BF, part);
    top1_softmax_kernel<<<dim3(TN * 16 / 256), dim3(256), 0, stream>>>(part, out);
}

// Round 16
// 43.393 us; speedup vs baseline: 1.0418x; 1.0418x over previous
//
#include <hip/hip_runtime.h>

typedef __attribute__((ext_vector_type(8))) short bf16x8;
typedef __attribute__((ext_vector_type(4))) float f32x4;

constexpr int TN = 8192;   // tokens
constexpr int DN = 4096;   // model dim
constexpr int EN = 64;     // experts

constexpr int BM = 64;         // rows per block (4 row-halves of 16)
constexpr int NS = DN / 32;    // 128 MFMA K32 slots total
constexpr int KSPLIT = 2;      // K halves -> grid 256 = 1 block/CU
constexpr int NTW = (NS / KSPLIT) / 8;  // 8 phases per wave

__device__ __forceinline__ unsigned short f2bf(float f) {  // RNE f32->bf16
    unsigned u = __builtin_bit_cast(unsigned, f);
    u += 0x7FFFu + ((u >> 16) & 1u);
    return (unsigned short)(u >> 16);
}
__device__ __forceinline__ float bf2f(unsigned short h) {
    unsigned u = ((unsigned)h) << 16;
    return __builtin_bit_cast(float, u);
}
// RNE hi/lo bf16 split of an f32 pair, packed (f1<<16|f0); ~14 VALU/pair.
__device__ __forceinline__ void split_pair(float f0, float f1,
                                           unsigned& hi, unsigned& lo) {
    unsigned u0 = __builtin_bit_cast(unsigned, f0);
    unsigned u1 = __builtin_bit_cast(unsigned, f1);
    unsigned r0 = u0 + 0x7FFFu + ((u0 >> 16) & 1u);
    unsigned r1 = u1 + 0x7FFFu + ((u1 >> 16) & 1u);
    hi = __builtin_amdgcn_perm(r1, r0, 0x07060302u);  // {r1.hi16, r0.hi16}
    float h0 = __builtin_bit_cast(float, r0 & 0xFFFF0000u);
    float h1 = __builtin_bit_cast(float, r1 & 0xFFFF0000u);
    unsigned v0 = __builtin_bit_cast(unsigned, f0 - h0);
    unsigned v1 = __builtin_bit_cast(unsigned, f1 - h1);
    unsigned s0 = v0 + 0x7FFFu + ((v0 >> 16) & 1u);
    unsigned s1 = v1 + 0x7FFFu + ((v1 >> 16) & 1u);
    lo = __builtin_amdgcn_perm(s1, s0, 0x07060302u);
}

// Kernel 0: split wg into hi/lo bf16 planes in MFMA-fragment order:
// BF[p][s][et][lane*8+j] = plane_p( wg[et*16+(lane&15)][s*32+(lane>>4)*8+j] ).
__global__ __launch_bounds__(256)
void wg_frag_kernel(const float* __restrict__ wg, unsigned short* __restrict__ BF) {
    const int gid = blockIdx.x * 256 + threadIdx.x;  // 65536 items
    const int l  = gid & 63;
    const int et = (gid >> 6) & 3;
    const int s  = (gid >> 8) & (NS - 1);
    const int p  = gid >> 15;
    const int e  = et * 16 + (l & 15);
    const int k  = s * 32 + (l >> 4) * 8;

    const float* src = wg + (size_t)e * DN + k;
    float4 v0 = *reinterpret_cast<const float4*>(src);
    float4 v1 = *reinterpret_cast<const float4*>(src + 4);
    float f[8] = {v0.x, v0.y, v0.z, v0.w, v1.x, v1.y, v1.z, v1.w};
    unsigned short o[8];
#pragma unroll
    for (int j = 0; j < 8; ++j) {
        unsigned short h = f2bf(f[j]);
        o[j] = p ? f2bf(f[j] - bf2f(h)) : h;
    }
    unsigned short* dst = BF + (((size_t)p * NS + s) * 4 + et) * 512 + (size_t)l * 8;
    *reinterpret_cast<ushort4*>(dst)     = make_ushort4(o[0], o[1], o[2], o[3]);
    *reinterpret_cast<ushort4*>(dst + 4) = make_ushort4(o[4], o[5], o[6], o[7]);
}

// Kernel 1: barrier-free direct-gather split-bf16 MFMA GEMM, BM=64.
// Grid = 128 row-tiles x 2 K-halves = 256 blocks (1/CU), 512 thr = 8
// INDEPENDENT waves. Wave w owns K32 slots ks*64 + t*8 + w (t=0..7) and
// computes FOUR 16-row halves per B fragment -- 16 VMEM instr per 64 rows
// vs the BM=32 winner's 12 per 32 (the measured pace is ~1 wide VMEM
// instr / ~50cyc / CU, so instruction count IS the time). A gathered
// per-lane from x, hi/lo split in-register. Depth-2 ping-pong both
// operands; FIFO order B-before-A so no wait drains a younger load.
__global__ __launch_bounds__(512, 2)
void gate_gemm_kernel(const float* __restrict__ x,
                      const unsigned short* __restrict__ BF,
                      float* __restrict__ part) {
    __shared__ float L[4][BM][68];      // 69632 B; 2-stage reduce buffer

    const int tid  = threadIdx.x;
    const int lane = tid & 63;
    const int w    = tid >> 6;          // wave 0..7
    const int rt   = blockIdx.x >> 1;
    const int ks   = blockIdx.x & 1;
    const int r0   = rt * BM;
    const int sbase = ks * (NS / KSPLIT);

    const int fr = lane & 15;           // fragment row (A) / expert col (B)
    const int g  = lane >> 4;           // k-group within K=32

    const float* xa = x + (size_t)(r0 + fr) * DN + g * 8;

    f32x4 acc[4][4] = {};               // [row-half][expert-tile] (64 VGPR)

    float4 XA[2][4][2];                 // depth-2 A fp32 [set][rh][2x float4]
    bf16x8 Bq[2][8];                    // depth-2 B [set][et]=hi, [set][4+et]=lo

    auto loadA = [&](int set, int t) {
        const int s = sbase + t * 8 + w;
        const float* p = xa + (size_t)s * 32;
#pragma unroll
        for (int rh = 0; rh < 4; ++rh) {
            const float* pr = p + (size_t)rh * 16 * DN;
            XA[set][rh][0] = *reinterpret_cast<const float4*>(pr);
            XA[set][rh][1] = *reinterpret_cast<const float4*>(pr + 4);
        }
    };
    auto loadB = [&](int set, int t) {
        const int s = sbase + t * 8 + w;
        const unsigned short* bp = BF + (size_t)s * 2048 + (size_t)lane * 8;
#pragma unroll
        for (int et = 0; et < 4; ++et)
            Bq[set][et] = *reinterpret_cast<const bf16x8*>(bp + et * 512);
#pragma unroll
        for (int et = 0; et < 4; ++et)
            Bq[set][4 + et] = *reinterpret_cast<const bf16x8*>(bp + (size_t)NS * 2048 + et * 512);
    };
    auto compute = [&](int set) {
        bf16x8 ah[4], al[4];
#pragma unroll
        for (int rh = 0; rh < 4; ++rh) {
            float f[8] = {XA[set][rh][0].x, XA[set][rh][0].y,
                          XA[set][rh][0].z, XA[set][rh][0].w,
                          XA[set][rh][1].x, XA[set][rh][1].y,
                          XA[set][rh][1].z, XA[set][rh][1].w};
            unsigned uh[4], ul[4];
#pragma unroll
            for (int q = 0; q < 4; ++q)
                split_pair(f[2 * q], f[2 * q + 1], uh[q], ul[q]);
            uint4 vh = make_uint4(uh[0], uh[1], uh[2], uh[3]);
            uint4 vl = make_uint4(ul[0], ul[1], ul[2], ul[3]);
            ah[rh] = __builtin_bit_cast(bf16x8, vh);
            al[rh] = __builtin_bit_cast(bf16x8, vl);
        }
        // product-outer order: 16 independent acc chains between reuses
#pragma unroll
        for (int et = 0; et < 4; ++et)
#pragma unroll
            for (int rh = 0; rh < 4; ++rh)
                acc[rh][et] = __builtin_amdgcn_mfma_f32_16x16x32_bf16(ah[rh], Bq[set][et], acc[rh][et], 0, 0, 0);
#pragma unroll
        for (int et = 0; et < 4; ++et)
#pragma unroll
            for (int rh = 0; rh < 4; ++rh)
                acc[rh][et] = __builtin_amdgcn_mfma_f32_16x16x32_bf16(al[rh], Bq[set][et], acc[rh][et], 0, 0, 0);
#pragma unroll
        for (int et = 0; et < 4; ++et)
#pragma unroll
            for (int rh = 0; rh < 4; ++rh)
                acc[rh][et] = __builtin_amdgcn_mfma_f32_16x16x32_bf16(ah[rh], Bq[set][4 + et], acc[rh][et], 0, 0, 0);
#pragma unroll
        for (int et = 0; et < 4; ++et)
#pragma unroll
            for (int rh = 0; rh < 4; ++rh)
                acc[rh][et] = __builtin_amdgcn_mfma_f32_16x16x32_bf16(al[rh], Bq[set][4 + et], acc[rh][et], 0, 0, 0);
    };

    // prologue FIFO: B(0),A(0),B(1),A(1) -- compute(0)'s wait for A(0)
    // (youngest needed) drains only B(0),A(0); set-1 loads stay in flight.
    loadB(0, 0);
    loadA(0, 0);
    loadB(1, 1);
    loadA(1, 1);
#pragma unroll
    for (int t = 0; t < NTW; ++t) {     // full unroll: set indices static
        compute(t & 1);
        if (t + 2 < NTW) { loadB(t & 1, t + 2); loadA(t & 1, t + 2); }
        asm volatile("" ::: "memory");  // pin per-phase issue order
    }

    // 2-stage cross-wave k-reduce: waves 0-3 write slot w, waves 4-7 add.
    // C/D layout: col = lane&15, row = (lane>>4)*4 + reg  [m89]
    if (w < 4) {
#pragma unroll
        for (int rh = 0; rh < 4; ++rh)
#pragma unroll
            for (int et = 0; et < 4; ++et)
#pragma unroll
                for (int r = 0; r < 4; ++r)
                    L[w][rh * 16 + g * 4 + r][et * 16 + fr] = acc[rh][et][r];
    }
    __syncthreads();
    if (w >= 4) {
#pragma unroll
        for (int rh = 0; rh < 4; ++rh)
#pragma unroll
            for (int et = 0; et < 4; ++et)
#pragma unroll
                for (int r = 0; r < 4; ++r)
                    L[w - 4][rh * 16 + g * 4 + r][et * 16 + fr] += acc[rh][et][r];
    }
    __syncthreads();

    {   // sum 4 slots, coalesced partial store: 8 threads/row, 8 experts each
        const int row = tid >> 3;       // 0..63
        const int eg  = tid & 7;
        float v[8];
#pragma unroll
        for (int j = 0; j < 8; ++j)
            v[j] = L[0][row][eg * 8 + j] + L[1][row][eg * 8 + j]
                 + L[2][row][eg * 8 + j] + L[3][row][eg * 8 + j];
        float* dst = part + ((size_t)ks * TN + r0 + row) * EN + eg * 8;
        *reinterpret_cast<float4*>(dst)     = make_float4(v[0], v[1], v[2], v[3]);
        *reinterpret_cast<float4*>(dst + 4) = make_float4(v[4], v[5], v[6], v[7]);
    }
}

// Kernel 2: sum 2 partials, top-1 softmax per row.
// out[0..TN) = argmax index (as float), out[TN..2TN) = max gate = 1/sumexp.
__global__ __launch_bounds__(256)
void top1_softmax_kernel(const float* __restrict__ part, float* __restrict__ out) {
    const int row = blockIdx.x * blockDim.x + threadIdx.x;
    if (row >= TN) return;

    float v[EN];
#pragma unroll
    for (int i = 0; i < EN / 4; ++i) {
        float4 s = *reinterpret_cast<const float4*>(&part[(size_t)row * EN + i * 4]);
        float4 t = *reinterpret_cast<const float4*>(&part[((size_t)TN + row) * EN + i * 4]);
        v[i * 4 + 0] = s.x + t.x; v[i * 4 + 1] = s.y + t.y;
        v[i * 4 + 2] = s.z + t.z; v[i * 4 + 3] = s.w + t.w;
    }

    float m = v[0];
    int idx = 0;
#pragma unroll
    for (int e = 1; e < EN; ++e)
        if (v[e] > m) { m = v[e]; idx = e; }  // strict >: first occurrence = jnp.argmax
    float s = 0.0f;
#pragma unroll
    for (int e = 0; e < EN; ++e) s += __expf(v[e] - m);

    out[row]      = (float)idx;
    out[TN + row] = 1.0f / s;
}

extern "C" void kernel_launch(void* const* d_in, const int* in_sizes, int n_in,
                              void* d_out, int out_size, void* d_ws, size_t ws_size,
                              hipStream_t stream) {
    const float* x  = (const float*)d_in[0];
    const float* wg = (const float*)d_in[1];
    float* out = (float*)d_out;

    constexpr size_t BF_BYTES = (size_t)2 * NS * 4 * 512 * 2;  // 1 MB
    unsigned short* BF = (unsigned short*)d_ws;
    float* part = (float*)((char*)d_ws + BF_BYTES);            // 4 MB partials

    wg_frag_kernel<<<dim3(256), dim3(256), 0, stream>>>(wg, BF);
    gate_gemm_kernel<<<dim3(128 * KSPLIT), dim3(512), 0, stream>>>(x, BF, part);
    top1_softmax_kernel<<<dim3(TN / 256), dim3(256), 0, stream>>>(part, out);
}

// Round 17
// 37.413 us; speedup vs baseline: 1.2083x; 1.1598x over previous
//
#include <hip/hip_runtime.h>

typedef __attribute__((ext_vector_type(8))) short bf16x8;
typedef __attribute__((ext_vector_type(4))) float f32x4;

constexpr int TN = 8192;   // tokens
constexpr int DN = 4096;   // model dim
constexpr int EN = 64;     // experts

constexpr int BM = 32;         // rows per block
constexpr int NS = DN / 32;    // 128 MFMA K32 slots
constexpr int NT = 16;         // slots per wave (128 / 8 waves)

__device__ __forceinline__ unsigned short f2bf(float f) {  // RNE f32->bf16
    unsigned u = __builtin_bit_cast(unsigned, f);
    u += 0x7FFFu + ((u >> 16) & 1u);
    return (unsigned short)(u >> 16);
}
__device__ __forceinline__ float bf2f(unsigned short h) {
    unsigned u = ((unsigned)h) << 16;
    return __builtin_bit_cast(float, u);
}

// Kernel 0: split wg into hi/lo bf16 planes in MFMA-fragment order WITH the
// k-permutation phi: fragment slot j of lane-group g holds physical k =
// s*32 + (j<4 ? g*4+j : 16+g*4+(j-4)). Same phi is used by the GEMM's A
// loads (dot product invariant when both operands share the permutation),
// making every A global-load instruction cover ONE 64B sector per row.
__global__ __launch_bounds__(256)
void wg_frag_kernel(const float* __restrict__ wg, unsigned short* __restrict__ BF) {
    const int gid = blockIdx.x * 256 + threadIdx.x;  // 65536 items
    const int l  = gid & 63;
    const int et = (gid >> 6) & 3;
    const int s  = (gid >> 8) & (NS - 1);
    const int p  = gid >> 15;
    const int e  = et * 16 + (l & 15);
    const int k  = s * 32 + (l >> 4) * 4;            // phi base

    const float* src = wg + (size_t)e * DN + k;
    float4 v0 = *reinterpret_cast<const float4*>(src);        // slots 0..3
    float4 v1 = *reinterpret_cast<const float4*>(src + 16);   // slots 4..7
    float f[8] = {v0.x, v0.y, v0.z, v0.w, v1.x, v1.y, v1.z, v1.w};
    unsigned short o[8];
#pragma unroll
    for (int j = 0; j < 8; ++j) {
        unsigned short h = f2bf(f[j]);
        o[j] = p ? f2bf(f[j] - bf2f(h)) : h;
    }
    unsigned short* dst = BF + (((size_t)p * NS + s) * 4 + et) * 512 + (size_t)l * 8;
    *reinterpret_cast<ushort4*>(dst)     = make_ushort4(o[0], o[1], o[2], o[3]);
    *reinterpret_cast<ushort4*>(dst + 4) = make_ushort4(o[4], o[5], o[6], o[7]);
}

// Kernel 1: barrier-free direct-gather split-bf16 MFMA GEMM + fused top-1.
// Grid = 256 blocks (1/CU), 512 threads = 8 INDEPENDENT waves (no in-loop
// __syncthreads). Wave w = (kq=w&3, kh=w>>2) owns K32 slots kh*64+t*4+kq,
// and computes both 16-row halves. A-fragments gathered per-lane from x
// using the phi k-permutation: lane (fr,g) instr0 reads row-bytes
// [s*128 + g*16 .. +16) (4 lane-groups = one 64B sector), instr1 the
// second sector -- 16 sector-touches/instr, the dense minimum (was 32).
// hi/lo split in-register; A depth-3 / B depth-2 ping-pong, full unroll.
__global__ __launch_bounds__(512, 2)
void gate_fused_kernel(const float* __restrict__ x,
                       const unsigned short* __restrict__ BF,
                       float* __restrict__ out) {
    __shared__ float L[8][BM][68];      // 69632 B; per-wave partial logits

    const int tid  = threadIdx.x;
    const int lane = tid & 63;
    const int w    = tid >> 6;          // wave 0..7
    const int kq   = w & 3;
    const int kh   = w >> 2;
    const int r0   = blockIdx.x * BM;

    const int fr = lane & 15;           // fragment row (A) / expert col (B)
    const int g  = lane >> 4;           // k-group

    // phi-permuted A base: row r0+fr, + g*4 floats within each 32-float slot
    const float* xa = x + (size_t)(r0 + fr) * DN + g * 4;

    f32x4 acc[2][4] = {};               // [row-half][expert-tile]

    float4 XA[3][2][2];                 // depth-3 A fp32 ([set][rh][2x float4])
    bf16x8 Bq[2][8];                    // depth-2 B ([set][et]=hi, [set][4+et]=lo)

    auto loadA = [&](int set, int t) {
        const int s = kh * 64 + t * 4 + kq;
        const float* p = xa + (size_t)s * 32;
#pragma unroll
        for (int rh = 0; rh < 2; ++rh) {
            const float* pr = p + (size_t)rh * 16 * DN;
            XA[set][rh][0] = *reinterpret_cast<const float4*>(pr);       // sector 0
            XA[set][rh][1] = *reinterpret_cast<const float4*>(pr + 16);  // sector 1
        }
    };
    auto loadB = [&](int set, int t) {
        const int s = kh * 64 + t * 4 + kq;
        const unsigned short* bp = BF + (size_t)s * 2048 + (size_t)lane * 8;
#pragma unroll
        for (int et = 0; et < 4; ++et)
            Bq[set][et] = *reinterpret_cast<const bf16x8*>(bp + et * 512);
#pragma unroll
        for (int et = 0; et < 4; ++et)
            Bq[set][4 + et] = *reinterpret_cast<const bf16x8*>(bp + (size_t)NS * 2048 + et * 512);
    };
    auto compute = [&](int aset, int bset) {
        bf16x8 ah[2], al[2];
#pragma unroll
        for (int rh = 0; rh < 2; ++rh) {
            float f[8] = {XA[aset][rh][0].x, XA[aset][rh][0].y,
                          XA[aset][rh][0].z, XA[aset][rh][0].w,
                          XA[aset][rh][1].x, XA[aset][rh][1].y,
                          XA[aset][rh][1].z, XA[aset][rh][1].w};
#pragma unroll
            for (int j = 0; j < 8; ++j) {
                unsigned short hh = f2bf(f[j]);
                ah[rh][j] = (short)hh;
                al[rh][j] = (short)f2bf(f[j] - bf2f(hh));
            }
        }
#pragma unroll
        for (int et = 0; et < 4; ++et)
#pragma unroll
            for (int rh = 0; rh < 2; ++rh) {
                acc[rh][et] = __builtin_amdgcn_mfma_f32_16x16x32_bf16(ah[rh], Bq[bset][et],     acc[rh][et], 0, 0, 0);
                acc[rh][et] = __builtin_amdgcn_mfma_f32_16x16x32_bf16(al[rh], Bq[bset][et],     acc[rh][et], 0, 0, 0);
                acc[rh][et] = __builtin_amdgcn_mfma_f32_16x16x32_bf16(ah[rh], Bq[bset][4 + et], acc[rh][et], 0, 0, 0);
                acc[rh][et] = __builtin_amdgcn_mfma_f32_16x16x32_bf16(al[rh], Bq[bset][4 + et], acc[rh][et], 0, 0, 0);
            }
    };

    // prologue FIFO: B(0), A(0), B(1), A(1), A(2)
    loadB(0, 0);
    loadA(0, 0);
    loadB(1, 1);
    loadA(1, 1);
    loadA(2, 2);
#pragma unroll
    for (int t = 0; t < NT; ++t) {      // full unroll: set indices static
        compute(t % 3, t & 1);
        if (t + 2 < NT) loadB(t & 1, t + 2);   // B BEFORE A (FIFO order)
        if (t + 3 < NT) loadA(t % 3, t + 3);
        asm volatile("" ::: "memory");  // pin per-phase issue order
    }

    // epilogue: per-wave partial logits to LDS, then fused top-1 softmax
#pragma unroll
    for (int rh = 0; rh < 2; ++rh)
#pragma unroll
        for (int et = 0; et < 4; ++et)
#pragma unroll
            for (int r = 0; r < 4; ++r)
                // C/D layout: col = lane&15, row = (lane>>4)*4 + reg  [m89]
                L[w][rh * 16 + g * 4 + r][et * 16 + fr] = acc[rh][et][r];
    __syncthreads();

    {
        const int row = tid >> 4;       // 0..31
        const int eg  = tid & 15;       // 4 experts each
        float v[4];
#pragma unroll
        for (int j = 0; j < 4; ++j) {
            float s = L[0][row][eg * 4 + j];
#pragma unroll
            for (int q = 1; q < 8; ++q) s += L[q][row][eg * 4 + j];
            v[j] = s;
        }
        float m = v[0];
        int idx = eg * 4;
#pragma unroll
        for (int j = 1; j < 4; ++j)
            if (v[j] > m) { m = v[j]; idx = eg * 4 + j; }  // strict >: first occurrence
#pragma unroll
        for (int d = 1; d < 16; d <<= 1) {
            float om = __shfl_xor(m, d);
            int   oi = __shfl_xor(idx, d);
            if (om > m || (om == m && oi < idx)) { m = om; idx = oi; }
        }
        float s = 0.0f;
#pragma unroll
        for (int j = 0; j < 4; ++j) s += __expf(v[j] - m);
#pragma unroll
        for (int d = 1; d < 16; d <<= 1) s += __shfl_xor(s, d);
        if (eg == 0) {
            out[r0 + row]      = (float)idx;     // argmax index
            out[TN + r0 + row] = 1.0f / s;       // max gate = 1/sum(exp(l-lmax))
        }
    }
}

extern "C" void kernel_launch(void* const* d_in, const int* in_sizes, int n_in,
                              void* d_out, int out_size, void* d_ws, size_t ws_size,
                              hipStream_t stream) {
    const float* x  = (const float*)d_in[0];
    const float* wg = (const float*)d_in[1];
    float* out = (float*)d_out;

    unsigned short* BF = (unsigned short*)d_ws;  // 1 MB fragment-ordered hi/lo

    wg_frag_kernel<<<dim3(256), dim3(256), 0, stream>>>(wg, BF);
    gate_fused_kernel<<<dim3(TN / BM), dim3(512), 0, stream>>>(x, BF, out);
}